// Round 14
// baseline (110134.058 us; speedup 1.0000x reference)
//
#include <hip/hip_runtime.h>

#define NBLK 256
#define NTHR 512

// ---------------- ws float offsets ----------------
#define OFF_PRE   0u            // [400][32][256]
#define OFF_PMT   3276800u      // [32][128][400]
#define OFF_GATT  4915200u      // [8][32][4096]
#define OFF_GDEC  5963776u      // [8][32][4096]
#define OFF_E     7012352u      // [32][400]
#define OFF_QP    7025152u      // [2][32][128]
#define OFF_AH    7033344u
#define OFF_AC0   7066112u
#define OFF_AC1   7098880u
#define OFF_DH    7131648u
#define OFF_DC    7164416u
#define OFF_AW0   7197184u
#define OFF_AW1   7209984u
#define OFF_AWC0  7222784u
#define OFF_AWC1  7235584u
#define OFF_CTX0  7248384u
#define OFF_CTX1  7264768u
#define OFF_BAR   7281152u      // hierarchical barrier lines (512 uints)
#define WS_TOTAL  7281664u      // 29.1 MB

#define LDS_FLOATS 12800        // xs [320][40] = 51,200 B (also reduce buffer 8192)

__device__ __forceinline__ float sigm(float x){ return 1.f/(1.f+__expf(-x)); }
__device__ __forceinline__ float ftanh(float x){
  x = fminf(fmaxf(x,-15.f),15.f);
  float e = __expf(2.f*x);
  return (e-1.f)/(e+1.f);
}

typedef __attribute__((ext_vector_type(4))) float f32x4;
typedef __attribute__((ext_vector_type(2))) float f32x2;

__device__ __forceinline__ float ldf(const float* p){
  return __hip_atomic_load(p, __ATOMIC_RELAXED, __HIP_MEMORY_SCOPE_SYSTEM);
}
__device__ __forceinline__ void stf(float* p, float v){
  __hip_atomic_store(p, v, __ATOMIC_RELAXED, __HIP_MEMORY_SCOPE_SYSTEM);
}
__device__ __forceinline__ void st_uc2(float* p, float2 v){
  f32x2 x = {v.x, v.y};
  asm volatile("global_store_dwordx2 %0, %1, off sc0 sc1" :: "v"(p), "v"(x) : "memory");
}
__device__ __forceinline__ unsigned uld(unsigned* p){
  return __hip_atomic_load(p, __ATOMIC_RELAXED, __HIP_MEMORY_SCOPE_SYSTEM);
}
__device__ __forceinline__ void ust(unsigned* p, unsigned v){
  __hip_atomic_store(p, v, __ATOMIC_RELAXED, __HIP_MEMORY_SCOPE_SYSTEM);
}
__device__ __forceinline__ unsigned ufadd(unsigned* p){
  return __hip_atomic_fetch_add(p, 1u, __ATOMIC_RELAXED, __HIP_MEMORY_SCOPE_SYSTEM);
}

// two-level fence-free grid barrier (R12-proven)
__device__ __forceinline__ void gsync(unsigned* bb){
  asm volatile("s_waitcnt vmcnt(0)" ::: "memory");
  __syncthreads();
  if (threadIdx.x==0){
    const int g = blockIdx.x & 7;
    unsigned* gcnt = bb + g*32;
    unsigned* ggen = bb + g*32 + 16;
    unsigned* mcnt = bb + 256;
    unsigned* mgen = bb + 256 + 16;
    unsigned gg = uld(ggen);
    unsigned arr = ufadd(gcnt);
    if (arr == 31u){
      unsigned mg = uld(mgen);
      unsigned ma = ufadd(mcnt);
      if (ma == 7u){
        ust(mcnt, 0u);
        asm volatile("s_waitcnt vmcnt(0)" ::: "memory");
        ufadd(mgen);
      } else {
        while (uld(mgen) == mg){ __builtin_amdgcn_s_sleep(2); }
      }
      ust(gcnt, 0u);
      asm volatile("s_waitcnt vmcnt(0)" ::: "memory");
      ufadd(ggen);
    } else {
      while (uld(ggen) == gg){ __builtin_amdgcn_s_sleep(2); }
    }
  }
  __syncthreads();
}

// -------------------- precompute --------------------

__global__ void zero_kernel(float* p, unsigned n){
  unsigned i = blockIdx.x*256u + threadIdx.x;
  if (i<n) p[i]=0.f;
}

__global__ __launch_bounds__(256) void prenet_kernel(const float* __restrict__ mel_target,
    const float* __restrict__ W1, const float* __restrict__ W2, float* __restrict__ pre)
{
  __shared__ float din[80];
  __shared__ float h1[256];
  int blk = blockIdx.x;          // t*32 + b
  int t = blk >> 5, b = blk & 31;
  int tid = threadIdx.x;
  if (tid < 80) din[tid] = (t==0) ? 0.f : mel_target[b*32000 + tid*400 + (t-1)];
  __syncthreads();
  float s=0.f;
  for (int c=0;c<80;c++) s += din[c]*W1[c*256+tid];
  h1[tid] = fmaxf(s,0.f);
  __syncthreads();
  float s2=0.f;
  for (int c=0;c<256;c++) s2 += h1[c]*W2[c*256+tid];
  pre[(size_t)blk*256 + tid] = fmaxf(s2,0.f);
}

__global__ __launch_bounds__(128) void pm_kernel(const float* __restrict__ memory,
    const float* __restrict__ memory_W, float* __restrict__ pmT)
{
  __shared__ float mrow[512];
  int blk = blockIdx.x;          // b*400 + t
  int b = blk/400, t = blk - b*400;
  int tid = threadIdx.x;
  const float* src = memory + (size_t)blk*512;
  for (int i=tid;i<512;i+=128) mrow[i]=src[i];
  __syncthreads();
  float s=0.f;
  for (int d=0; d<512; d++) s += mrow[d]*memory_W[d*128+tid];
  pmT[(size_t)b*51200 + tid*400 + t] = s;
}

// -------------------- W phase: register-streaming gates GEMM --------------------
// Block (cb=bid&31, kh=bid>>5). Wave wv owns k-rows [kh*SLICE + wv*KPW, +KPW);
// thread owns 2 cols (cb*128 + lane*2) x 32 batches in registers (64 acc VGPRs).
// Weights: plain cached dwordx2 loads (512B/wave/row, coalesced), no LDS for
// weights, no barriers in the K loop. x staged once per slice into LDS [kk][40].
// After the K loop: in-block reduction across the 8 waves (4 chunks of 8
// batches through LDS) -> one UC float2 store per output. (R13 bug: waves
// raced their k-partials into the same Gp slot; this reduce is the fix.)
template<int SLICE, int KIH, bool IMM0>
__device__ __forceinline__ void gemm_stream(float* xs, int k_beg, int cb,
    const float* x0, int n0, const float* x1, int n1, const float* x2, int n2,
    const float* __restrict__ Wih, const float* __restrict__ Whh, float* Gp)
{
  const int tid = threadIdx.x;
  const int n01 = n0 + n1;
  __syncthreads();                       // previous users of xs done
  for (int base=0; base<32*SLICE; base+=NTHR){
    int idx = base + tid;
    if (idx < 32*SLICE){
      int r = idx / SLICE, kk = idx - r*SLICE;
      int k = k_beg + kk;
      float v;
      if (k < n0) v = IMM0 ? x0[r*n0 + k] : ldf(x0 + r*n0 + k);
      else if (k < n01) v = ldf(x1 + r*n1 + (k-n0));
      else v = ldf(x2 + r*n2 + (k-n01));
      xs[kk*40 + r] = v;
    }
  }
  __syncthreads();
  const int wv = tid>>6, lane = tid&63;
  constexpr int KPW = SLICE/8;           // k rows per wave
  const int kk0 = wv*KPW;
  const int colE = cb*128 + lane*2;      // first owned column
  float acc0[32], acc1[32];
  #pragma unroll
  for (int b=0;b<32;b++){ acc0[b]=0.f; acc1[b]=0.f; }
  for (int i=0; i<KPW; i+=4){
    float2 w[4];
    #pragma unroll
    for (int j=0;j<4;j++){
      int k = k_beg + kk0 + i + j;       // wave-uniform row
      const float* row = (k < KIH) ? (Wih + (size_t)k*4096)
                                   : (Whh + (size_t)(k-KIH)*4096);
      w[j] = *(const float2*)(row + colE);
    }
    #pragma unroll
    for (int j=0;j<4;j++){
      const float* xk = xs + (kk0+i+j)*40;
      #pragma unroll
      for (int q=0;q<8;q++){
        float4 xb = *(const float4*)(xk + q*4);
        acc0[q*4+0] += w[j].x*xb.x; acc1[q*4+0] += w[j].y*xb.x;
        acc0[q*4+1] += w[j].x*xb.y; acc1[q*4+1] += w[j].y*xb.y;
        acc0[q*4+2] += w[j].x*xb.z; acc1[q*4+2] += w[j].y*xb.z;
        acc0[q*4+3] += w[j].x*xb.w; acc1[q*4+3] += w[j].y*xb.w;
      }
    }
  }
  // cross-wave reduction: 4 chunks of 8 batches via LDS (reuses xs, 8192 floats)
  const int lc = lane*2;
  const int jr = tid >> 6, cr = (tid & 63)*2;
  for (int ch=0; ch<4; ch++){
    __syncthreads();                     // xs free (K loops / prev chunk done)
    #pragma unroll
    for (int j=0;j<8;j++){
      xs[(wv*8 + j)*128 + lc    ] = acc0[ch*8 + j];
      xs[(wv*8 + j)*128 + lc + 1] = acc1[ch*8 + j];
    }
    __syncthreads();
    float2 s = {0.f, 0.f};
    #pragma unroll
    for (int w2=0; w2<8; w2++){
      s.x += xs[(w2*8 + jr)*128 + cr];
      s.y += xs[(w2*8 + jr)*128 + cr + 1];
    }
    st_uc2(Gp + (size_t)(ch*8 + jr)*4096 + cb*128 + cr, s);
  }
}

__device__ __forceinline__ void w_phase(float* sm,
    const float* pre_t, const float* CTXp, const float* AH, const float* DH,
    const float* att_Wih, const float* att_Whh, float* GATT,
    const float* dec_Wih, const float* dec_Whh, float* GDEC,
    bool do_att, bool do_dec)
{
  const int bid = blockIdx.x;
  const int cb = bid & 31, kh = bid >> 5;
  float* xs = sm;                        // [320][40] max
  if (do_att)
    gemm_stream<224,768,true>(xs, kh*224, cb, pre_t,256, CTXp,512, AH,1024,
                              att_Wih, att_Whh, GATT + (size_t)kh*131072);
  if (do_dec)
    gemm_stream<320,1536,false>(xs, kh*320, cb, AH,1024, CTXp,512, DH,1024,
                                dec_Wih, dec_Whh, GDEC + (size_t)kh*131072);
}

// -------------------- B1: reduce + LSTM pointwise + q halves --------------------
__device__ __forceinline__ void b1_phase(float* sm,
    const float* GATT, const float* GDEC,
    const float* att_b, const float* dec_b, const float* query_W,
    float* AH, const float* ACr, float* ACw, float* DH, float* DC,
    float* QP, int step)
{
  const int bid = blockIdx.x, tid = threadIdx.x;
  const int b = bid & 31, role = bid >> 5;
  if (role < 2){
    float* ah_s = sm;          // 512
    float* pool = sm + 512;    // 512
    const int h = role;
    const int u = h*512 + tid;
    float g4[4];
    #pragma unroll
    for (int g=0; g<4; g++){
      float s = att_b[g*1024 + u];
      #pragma unroll
      for (int sl=0; sl<8; sl++)
        s += ldf(GATT + (size_t)sl*131072 + (size_t)b*4096 + g*1024 + u);
      g4[g] = s;
    }
    float c = sigm(g4[1])*ldf(ACr + b*1024 + u) + sigm(g4[0])*ftanh(g4[2]);
    float hv = sigm(g4[3])*ftanh(c);
    stf(ACw + b*1024 + u, c);
    stf(AH  + b*1024 + u, hv);
    ah_s[tid] = hv;
    __syncthreads();
    { int a = tid & 127, sl = tid >> 7;
      float s = 0.f; int kb = sl*128;
      for (int k=kb; k<kb+128; k++) s += ah_s[k]*query_W[(h*512+k)*128 + a];
      pool[sl*128+a] = s; }
    __syncthreads();
    if (tid < 128)
      stf(QP + h*4096 + b*128 + tid,
          pool[tid]+pool[128+tid]+pool[256+tid]+pool[384+tid]);
  } else if (role < 4 && step > 0){
    const int h = role - 2;
    const int u = h*512 + tid;
    float g4[4];
    #pragma unroll
    for (int g=0; g<4; g++){
      float s = dec_b[g*1024 + u];
      #pragma unroll
      for (int sl=0; sl<8; sl++)
        s += ldf(GDEC + (size_t)sl*131072 + (size_t)b*4096 + g*1024 + u);
      g4[g] = s;
    }
    float c = sigm(g4[1])*ldf(DC + b*1024 + u) + sigm(g4[0])*ftanh(g4[2]);
    float hv = sigm(g4[3])*ftanh(c);
    stf(DC + b*1024 + u, c);
    stf(DH + b*1024 + u, hv);
  }
}

// -------------------- B2: conv + energies (b=bid&31, chunk yD of 50 t) --------------------
__device__ __forceinline__ void b2_phase(float* sm,
    const float* wcv, const float* wdv, const float* vvec,
    const float* pmT, const int* mlen,
    const float* AWr, const float* AWCr, const float* QP, float* E)
{
  float* aw_s = sm;         // 400
  float* awc_s= sm+400;     // 400
  float* wc_s = sm+800;     // 1984
  float* wd_s = sm+2784;    // 4096
  float* v_s  = sm+6880;    // 128
  float* q_s  = sm+7008;    // 128
  float* loc  = sm+7136;    // 50*33 = 1650
  float* ep   = sm+8800;    // 8*64
  const int bid = blockIdx.x, tid = threadIdx.x;
  const int b = bid & 31, yD = bid >> 5;
  for (int i=tid;i<400;i+=NTHR){ aw_s[i]=ldf(AWr+b*400+i); awc_s[i]=ldf(AWCr+b*400+i); }
  for (int i=tid;i<4096;i+=NTHR) wd_s[i]=wdv[i];
  for (int i=tid;i<1984;i+=NTHR) wc_s[i]=wcv[i];
  if (tid<128){
    v_s[tid]=vvec[tid];
    q_s[tid] = ldf(QP + b*128 + tid) + ldf(QP + 4096 + b*128 + tid);
  }
  __syncthreads();
  const int t0 = yD*50;
  { int tl = tid & 63, fs = tid >> 6;
    if (tl < 50){
      float cf0=0,cf1=0,cf2=0,cf3=0;
      int f0 = fs*4;
      int tg = t0 + tl;
      for (int k=0;k<31;k++){
        int gi2 = tg + k - 15;
        float a1 = (gi2>=0 && gi2<400) ? aw_s[gi2] : 0.f;
        float a2 = (gi2>=0 && gi2<400) ? awc_s[gi2] : 0.f;
        cf0 += wc_s[(f0+0)*62+k]*a1 + wc_s[(f0+0)*62+31+k]*a2;
        cf1 += wc_s[(f0+1)*62+k]*a1 + wc_s[(f0+1)*62+31+k]*a2;
        cf2 += wc_s[(f0+2)*62+k]*a1 + wc_s[(f0+2)*62+31+k]*a2;
        cf3 += wc_s[(f0+3)*62+k]*a1 + wc_s[(f0+3)*62+31+k]*a2;
      }
      loc[tl*33+f0+0]=cf0; loc[tl*33+f0+1]=cf1;
      loc[tl*33+f0+2]=cf2; loc[tl*33+f0+3]=cf3;
    }
  }
  __syncthreads();
  { int tl = tid & 63, as = tid >> 6;
    if (tl < 50){
      int tg = t0 + tl;
      float e = 0.f;
      const float* lrow = loc + tl*33;
      for (int aa=0; aa<16; aa++){
        int a = as*16 + aa;
        float pmv = pmT[(size_t)b*51200 + (size_t)a*400 + tg];
        float lv = 0.f;
        #pragma unroll
        for (int f=0; f<32; f++) lv += lrow[f]*wd_s[f*128+a];
        e += ftanh(q_s[a]+pmv+lv)*v_s[a];
      }
      ep[as*64+tl] = e;
    }
  }
  __syncthreads();
  if (tid < 50){
    int tg = t0 + tid;
    float ee=0.f;
    #pragma unroll
    for (int as2=0; as2<8; as2++) ee += ep[as2*64+tid];
    stf(E + b*400 + tg, (tg < mlen[b]) ? ee : -1e30f);
  }
}

// -------------------- C: softmax + ctx + proj(t-1) --------------------
__device__ __forceinline__ void c_phase(float* sm, const float* E, const float* memory,
    float* AWw, const float* AWCr, float* AWCw,
    float* CTXw, const float* CTXpp, const float* DH,
    const float* proj_W, const float* proj_b,
    const float* gate_W, const float* gate_b,
    float* out, float* aligns, int step)
{
  float* e_s = sm;           // 400
  float* red = sm+400;       // 16
  float* cp  = sm+416;       // 512
  float* do_s= sm+928;       // 1536
  float* pps = sm+2464;      // 486
  const int bid = blockIdx.x, tid = threadIdx.x;
  const int b = bid & 31, yD = bid >> 5;

  float ev = (tid<400) ? ldf(E+b*400+tid) : -1e30f;
  float m = ev;
  for (int off=32; off>0; off>>=1) m = fmaxf(m, __shfl_down(m, off, 64));
  if ((tid&63)==0) red[tid>>6]=m;
  __syncthreads();
  if (tid==0){ float mm=red[0]; for (int i=1;i<8;i++) mm=fmaxf(mm,red[i]); red[8]=mm; }
  __syncthreads();
  m = red[8];
  float ex = (tid<400) ? __expf(ev-m) : 0.f;
  float ss = ex;
  for (int off=32; off>0; off>>=1) ss += __shfl_down(ss, off, 64);
  if ((tid&63)==0) red[tid>>6]=ss;
  __syncthreads();
  if (tid==0){ float s2=0.f; for (int i=0;i<8;i++) s2+=red[i]; red[9]=1.f/s2; }
  __syncthreads();
  float anew = ex*red[9];
  if (tid<400) e_s[tid]=anew;
  if (yD==0 && tid<400){
    stf(AWw+b*400+tid, anew);
    stf(AWCw+b*400+tid, ldf(AWCr+b*400+tid) + anew);
    aligns[(size_t)b*160000 + (size_t)step*400 + tid] = anew;
  }
  __syncthreads();
  { int d = tid & 63, ts = tid >> 6;
    const int d0 = yD*64;
    const float* mrow = memory + (size_t)b*204800 + d0 + d;
    float pacc=0.f;
    for (int tt=ts*50; tt<ts*50+50; tt++) pacc += e_s[tt]*mrow[(size_t)tt*512];
    cp[ts*64+d]=pacc; }
  __syncthreads();
  if (tid<64){
    float s2=0.f;
    #pragma unroll
    for (int ts2=0; ts2<8; ts2++) s2+=cp[ts2*64+tid];
    stf(CTXw + b*512 + yD*64 + tid, s2);
  }
  if (yD==0 && step>0){
    for (int i=tid; i<1536; i+=NTHR)
      do_s[i] = (i<1024) ? ldf(DH+b*1024+i) : ldf(CTXpp+b*512 + (i-1024));
    __syncthreads();
    int sl = tid/81, o = tid - sl*81;
    if (sl < 6){
      float s=0.f; int kb = sl*256;
      for (int k=kb;k<kb+256;k++){
        float w2 = (o<80) ? proj_W[k*80+o] : gate_W[k];
        s += do_s[k]*w2;
      }
      pps[sl*81+o]=s;
    }
    __syncthreads();
    if (tid<81){
      float r=0.f;
      #pragma unroll
      for (int s2=0;s2<6;s2++) r += pps[s2*81+tid];
      if (tid<80) out[(size_t)b*32000 + tid*400 + (step-1)] = r + proj_b[tid];
      else        out[1024000 + b*400 + (step-1)] = r + gate_b[0];
    }
  }
}

// -------------------- epilogue: dec step 399 --------------------
__device__ __forceinline__ void dec_final_phase(float* sm,
    const float* Gd, const float* dec_b,
    const float* DC, const float* CTX1,
    const float* proj_W, const float* proj_b,
    const float* gate_W, const float* gate_b, float* out)
{
  float* do_s = sm;       // 1536
  float* pps  = sm+1536;  // 486
  const int b = blockIdx.x, tid = threadIdx.x;
  for (int u0=0; u0<2; u0++){
    int u = tid + u0*512;
    float g4[4];
    #pragma unroll
    for (int g=0; g<4; g++){
      float s = dec_b[g*1024 + u];
      #pragma unroll
      for (int sl=0; sl<8; sl++)
        s += ldf(Gd + (size_t)sl*131072 + (size_t)b*4096 + g*1024 + u);
      g4[g] = s;
    }
    float c = sigm(g4[1])*ldf(DC + b*1024 + u) + sigm(g4[0])*ftanh(g4[2]);
    do_s[u] = sigm(g4[3])*ftanh(c);
  }
  do_s[1024+tid] = ldf(CTX1 + b*512 + tid);
  __syncthreads();
  int sl = tid/81, o = tid - sl*81;
  if (sl < 6){
    float s=0.f; int kb = sl*256;
    for (int k=kb;k<kb+256;k++){
      float w2 = (o<80) ? proj_W[k*80+o] : gate_W[k];
      s += do_s[k]*w2;
    }
    pps[sl*81+o]=s;
  }
  __syncthreads();
  if (tid<81){
    float r=0.f;
    #pragma unroll
    for (int s2=0;s2<6;s2++) r += pps[s2*81+tid];
    if (tid<80) out[(size_t)b*32000 + tid*400 + 399] = r + proj_b[tid];
    else        out[1024000 + b*400 + 399] = r + gate_b[0];
  }
}

// -------------------- persistent cooperative kernel --------------------
__global__ void __launch_bounds__(NTHR) decoder_persist(
    const float* memory, const int* mlen, const float* query_W,
    const float* wcv, const float* wdv, const float* vvec,
    const float* att_Wih, const float* att_Whh, const float* att_b,
    const float* dec_Wih, const float* dec_Whh, const float* dec_b,
    const float* proj_W, const float* proj_b,
    const float* gate_W, const float* gate_b,
    float* ws, float* out)
{
  extern __shared__ float sm[];
  float* PRE  = ws + OFF_PRE;
  float* PMT  = ws + OFF_PMT;
  float* GATT = ws + OFF_GATT;
  float* GDEC = ws + OFF_GDEC;
  float* E    = ws + OFF_E;
  float* QP   = ws + OFF_QP;
  float* AH   = ws + OFF_AH;
  float* AC_[2] = { ws + OFF_AC0, ws + OFF_AC1 };
  float* DH   = ws + OFF_DH;
  float* DC   = ws + OFF_DC;
  float* AW_[2] = { ws + OFF_AW0, ws + OFF_AW1 };
  float* AWC_[2]= { ws + OFF_AWC0, ws + OFF_AWC1 };
  float* CTX_[2]= { ws + OFF_CTX0, ws + OFF_CTX1 };
  unsigned* bar = (unsigned*)(ws + OFF_BAR);
  float* aligns = out + 1036800;

  // prologue: GATT(0) from zero state
  w_phase(sm, PRE, CTX_[1], AH, DH, att_Wih, att_Whh, GATT,
          dec_Wih, dec_Whh, GDEC, true, false);
  gsync(bar);

  for (int t=0; t<400; t++){
    const int p = t & 1, pp = 1 - p;
    // B1: att reduce+pw+q halves; dec pw of t-1
    b1_phase(sm, GATT, GDEC, att_b, dec_b, query_W,
             AH, AC_[pp], AC_[p], DH, DC, QP, t);
    gsync(bar);
    // B2: conv + energies
    b2_phase(sm, wcv, wdv, vvec, PMT, mlen, AW_[pp], AWC_[pp], QP, E);
    gsync(bar);
    // C: softmax + ctx + proj(t-1)
    c_phase(sm, E, memory, AW_[p], AWC_[pp], AWC_[p], CTX_[p], CTX_[pp],
            DH, proj_W, proj_b, gate_W, gate_b, out, aligns, t);
    gsync(bar);
    // W: GATT(t+1) [skip at 399] + GDEC(t)
    w_phase(sm, (t<399) ? (PRE + (size_t)(t+1)*8192) : PRE, CTX_[p], AH, DH,
            att_Wih, att_Whh, GATT, dec_Wih, dec_Whh, GDEC, t<399, true);
    gsync(bar);
  }
  if (blockIdx.x < 32)
    dec_final_phase(sm, GDEC, dec_b, DC, CTX_[1],
                    proj_W, proj_b, gate_W, gate_b, out);
}

// -------------------- launch --------------------

extern "C" void kernel_launch(void* const* d_in, const int* in_sizes, int n_in,
                              void* d_out, int out_size, void* d_ws, size_t ws_size,
                              hipStream_t stream) {
  const float* memory      = (const float*)d_in[0];
  const float* mel_target  = (const float*)d_in[1];
  const int*   mlen        = (const int*)  d_in[2];
  const float* prenet_W1   = (const float*)d_in[3];
  const float* prenet_W2   = (const float*)d_in[4];
  const float* query_W     = (const float*)d_in[5];
  const float* memory_W    = (const float*)d_in[6];
  const float* weight_vec  = (const float*)d_in[7];
  const float* loc_conv_W  = (const float*)d_in[8];
  const float* loc_dense_W = (const float*)d_in[9];
  const float* att_Wih     = (const float*)d_in[10];
  const float* att_Whh     = (const float*)d_in[11];
  const float* att_b       = (const float*)d_in[12];
  const float* dec_Wih     = (const float*)d_in[13];
  const float* dec_Whh     = (const float*)d_in[14];
  const float* dec_b       = (const float*)d_in[15];
  const float* proj_W      = (const float*)d_in[16];
  const float* proj_b      = (const float*)d_in[17];
  const float* gate_W      = (const float*)d_in[18];
  const float* gate_b      = (const float*)d_in[19];
  float* out = (float*)d_out;
  float* ws  = (float*)d_ws;

  float* PRE = ws + OFF_PRE;
  float* PMT = ws + OFF_PMT;

  // zero the entire used workspace every call -> replay-deterministic
  hipLaunchKernelGGL(zero_kernel, dim3((WS_TOTAL+255u)/256u), dim3(256), 0, stream, ws, WS_TOTAL);
  hipLaunchKernelGGL(prenet_kernel, dim3(12800), dim3(256), 0, stream,
                     mel_target, prenet_W1, prenet_W2, PRE);
  hipLaunchKernelGGL(pm_kernel, dim3(12800), dim3(128), 0, stream, memory, memory_W, PMT);

  void* args[] = {
    (void*)&memory, (void*)&mlen, (void*)&query_W,
    (void*)&loc_conv_W, (void*)&loc_dense_W, (void*)&weight_vec,
    (void*)&att_Wih, (void*)&att_Whh, (void*)&att_b,
    (void*)&dec_Wih, (void*)&dec_Whh, (void*)&dec_b,
    (void*)&proj_W, (void*)&proj_b, (void*)&gate_W, (void*)&gate_b,
    (void*)&ws, (void*)&out
  };
  hipLaunchCooperativeKernel((const void*)decoder_persist, dim3(NBLK), dim3(NTHR),
                             args, LDS_FLOATS*sizeof(float), stream);
}